// Round 18
// baseline (29.086 us; speedup 1.0000x reference)
//
#include <hip/hip_runtime.h>
#include <math.h>

// ---- compile-time problem constants (from setup_inputs) ----
#define B_SZ 2
#define HI 48
#define WI 48
#define NG (HI*WI)          // 2304 gaussians per image
#define NT (B_SZ*NG)        // 4608 total gaussians
#define HIDN 256
#define HT 96
#define WT 96
#define PT (HT*WT)          // 9216 pixels per image
#define FACTOR 2.0f         // max(96/48, 96/48)
#define OFF_SCALE 0.125f    // 3 * (2*factor / max(Ht,Wt))
#define A_MIN (1.0f/255.0f)
#define A_MAX 0.99f
#define LN255 5.54126354516f   // ln(255): w >= 1/255 <=> sigma <= LN255

#define GPB 6               // gaussians per block: 4608/6 = 768 blocks = 3/CU EXACTLY
#define RTS 8               // render tile size (8x8 px, 64 px x 4 slices, 256 thr)

// ws layout: ga[NT] f4 | gb[NT] f4 | gt[NT] f4

__global__ __launch_bounds__(256, 3) void param_kernel(
    const float* __restrict__ inp, const float* __restrict__ enc_w, const float* __restrict__ enc_b,
    const float* __restrict__ ow1, const float* __restrict__ ob1, const float* __restrict__ ow2, const float* __restrict__ ob2,
    const float* __restrict__ sw1, const float* __restrict__ sb1, const float* __restrict__ sw2, const float* __restrict__ sb2,
    const float* __restrict__ rw1, const float* __restrict__ rb1, const float* __restrict__ rw2, const float* __restrict__ rb2,
    const float* __restrict__ cw1, const float* __restrict__ cb1, const float* __restrict__ cw2, const float* __restrict__ cb2,
    float4* __restrict__ ga, float4* __restrict__ gb, float4* __restrict__ gt)
{
    __shared__ float sinp[3][3][12];                 // input patch: 3ch x 3 rows x 8 cols (pad 12)
    __shared__ __align__(16) float feat[GPB][68];    // conv output, float4-readable
    __shared__ __align__(16) float hid[4][GPB][260]; // layer-1 output, stride 260
    __shared__ __align__(16) float w2t[8][260];      // transposed layer-2 weights: w2t[o][k]
    __shared__ float red[192];
    __shared__ float outv[GPB][8];

    const int t  = threadIdx.x;
    const int n0 = blockIdx.x * GPB;
    const int b  = n0 / NG;
    const int pix0 = n0 % NG;
    const int y  = pix0 / WI;
    const int x0 = pix0 % WI;     // block's 6 pixels: (y, x0..x0+5), same row

    // ---- stage input patch + transposed w2 to LDS ----
    if (t < 72) {                 // 3 ch x 3 rows x 8 cols
        int c = t / 24, r = (t / 8) % 3, cc = t % 8;
        int yy = y + r - 1;
        int xx = x0 + cc - 1;
        float v = 0.f;
        if (yy >= 0 && yy < HI && xx >= 0 && xx < WI)
            v = inp[((b*3 + c)*HI + yy)*WI + xx];
        sinp[c][r][cc] = v;
    }
    for (int i = t; i < 2048; i += 256) {
        int o = i >> 8, k = i & 255;
        float v;
        if (o < 2)      v = ow2[k*2 + o];
        else if (o < 4) v = sw2[k*2 + (o-2)];
        else if (o < 5) v = rw2[k];
        else            v = cw2[k*3 + (o-5)];
        w2t[o][k] = v;
    }
    __syncthreads();

    // ---- conv 3x3 SAME: weights in VGPRs (o = t&63 invariant); 384 tasks ----
    {
        const int o = t & 63;
        float w[27];
        #pragma unroll
        for (int j = 0; j < 27; ++j) w[j] = enc_w[o*27 + j];
        const float bias = enc_b[o];
        #pragma unroll
        for (int rep = 0; rep < 2; ++rep) {
            int idx = rep * 256 + t;
            if (idx < GPB*64) {
                int gi = idx >> 6;
                float acc = bias;
                #pragma unroll
                for (int c = 0; c < 3; ++c)
                    #pragma unroll
                    for (int ky = 0; ky < 3; ++ky)
                        #pragma unroll
                        for (int kx = 0; kx < 3; ++kx)
                            acc += w[c*9 + ky*3 + kx] * sinp[c][ky][gi + kx];
                feat[gi][o] = acc;
            }
        }
    }
    __syncthreads();

    // ---- layer 1: thread = (mlp m, h-quad); DEPTH-2 pipelined weight loads ----
    const int m  = t >> 6;          // wave-uniform
    const int h0 = (t & 63) * 4;
    {
        const float* __restrict__ w1 = (m == 0) ? ow1 : (m == 1) ? sw1 : (m == 2) ? rw1 : cw1;
        const float* __restrict__ b1 = (m == 0) ? ob1 : (m == 1) ? sb1 : (m == 2) ? rb1 : cb1;
        float acc[4][GPB];
        #pragma unroll
        for (int hh = 0; hh < 4; ++hh)
            #pragma unroll
            for (int gi = 0; gi < GPB; ++gi) acc[hh][gi] = 0.f;

        // prefetch groups 0 and 1 (depth-2 pipeline)
        float4 wA0 = *(const float4*)&w1[0*HIDN + h0];
        float4 wA1 = *(const float4*)&w1[1*HIDN + h0];
        float4 wA2 = *(const float4*)&w1[2*HIDN + h0];
        float4 wA3 = *(const float4*)&w1[3*HIDN + h0];
        float4 wB0 = *(const float4*)&w1[4*HIDN + h0];
        float4 wB1 = *(const float4*)&w1[5*HIDN + h0];
        float4 wB2 = *(const float4*)&w1[6*HIDN + h0];
        float4 wB3 = *(const float4*)&w1[7*HIDN + h0];

        for (int it = 0; it < 14; ++it) {           // groups 0..13, prefetch it+2
            float4 wC0 = *(const float4*)&w1[(it*4 + 8)*HIDN + h0];
            float4 wC1 = *(const float4*)&w1[(it*4 + 9)*HIDN + h0];
            float4 wC2 = *(const float4*)&w1[(it*4 + 10)*HIDN + h0];
            float4 wC3 = *(const float4*)&w1[(it*4 + 11)*HIDN + h0];
            #pragma unroll
            for (int gi = 0; gi < GPB; ++gi) {
                float4 f = *(const float4*)&feat[gi][it*4];
                acc[0][gi] += f.x*wA0.x + f.y*wA1.x + f.z*wA2.x + f.w*wA3.x;
                acc[1][gi] += f.x*wA0.y + f.y*wA1.y + f.z*wA2.y + f.w*wA3.y;
                acc[2][gi] += f.x*wA0.z + f.y*wA1.z + f.z*wA2.z + f.w*wA3.z;
                acc[3][gi] += f.x*wA0.w + f.y*wA1.w + f.z*wA2.w + f.w*wA3.w;
            }
            wA0 = wB0; wA1 = wB1; wA2 = wB2; wA3 = wB3;
            wB0 = wC0; wB1 = wC1; wB2 = wC2; wB3 = wC3;
        }
        // peeled groups 14, 15 (k = 56..63)
        #pragma unroll
        for (int gi = 0; gi < GPB; ++gi) {
            float4 f = *(const float4*)&feat[gi][56];
            acc[0][gi] += f.x*wA0.x + f.y*wA1.x + f.z*wA2.x + f.w*wA3.x;
            acc[1][gi] += f.x*wA0.y + f.y*wA1.y + f.z*wA2.y + f.w*wA3.y;
            acc[2][gi] += f.x*wA0.z + f.y*wA1.z + f.z*wA2.z + f.w*wA3.z;
            acc[3][gi] += f.x*wA0.w + f.y*wA1.w + f.z*wA2.w + f.w*wA3.w;
        }
        #pragma unroll
        for (int gi = 0; gi < GPB; ++gi) {
            float4 f = *(const float4*)&feat[gi][60];
            acc[0][gi] += f.x*wB0.x + f.y*wB1.x + f.z*wB2.x + f.w*wB3.x;
            acc[1][gi] += f.x*wB0.y + f.y*wB1.y + f.z*wB2.y + f.w*wB3.y;
            acc[2][gi] += f.x*wB0.z + f.y*wB1.z + f.z*wB2.z + f.w*wB3.z;
            acc[3][gi] += f.x*wB0.w + f.y*wB1.w + f.z*wB2.w + f.w*wB3.w;
        }

        // effective bias: b1 + FACTOR * w1[k=64 row]  (feat[64] == FACTOR const)
        float4 bb = *(const float4*)&b1[h0];
        float4 wl = *(const float4*)&w1[64*HIDN + h0];
        bb.x += FACTOR * wl.x; bb.y += FACTOR * wl.y;
        bb.z += FACTOR * wl.z; bb.w += FACTOR * wl.w;
        #pragma unroll
        for (int gi = 0; gi < GPB; ++gi) {
            float4 hv;
            hv.x = fmaxf(acc[0][gi] + bb.x, 0.f);
            hv.y = fmaxf(acc[1][gi] + bb.y, 0.f);
            hv.z = fmaxf(acc[2][gi] + bb.z, 0.f);
            hv.w = fmaxf(acc[3][gi] + bb.w, 0.f);
            *(float4*)&hid[m][gi][h0] = hv;
        }
    }
    __syncthreads();

    // ---- layer 2: 48 (gi,o) pairs x 4 k-chunks = 192 tasks ----
    if (t < 192) {
        int pair = t % 48, q = t / 48;
        int o = pair & 7, gi = pair >> 3;
        int mm = (o < 2) ? 0 : (o < 4) ? 1 : (o < 5) ? 2 : 3;
        float p = 0.f;
        int k0 = q * 64;
        #pragma unroll
        for (int kk = 0; kk < 16; ++kk) {
            float4 hv = *(const float4*)&hid[mm][gi][k0 + kk*4];
            float4 wv = *(const float4*)&w2t[o][k0 + kk*4];
            p += hv.x*wv.x + hv.y*wv.y + hv.z*wv.z + hv.w*wv.w;
        }
        red[t] = p;
    }
    __syncthreads();
    if (t < 48) {
        int o = t & 7;
        float v = red[t] + red[t+48] + red[t+96] + red[t+144];
        float b2 = (o < 2) ? ob2[o] : (o < 4) ? sb2[o-2] : (o < 5) ? rb2[0] : cb2[o-5];
        outv[t >> 3][o] = v + b2;
    }
    __syncthreads();

    // ---- activations + projection + conic + cull radii ----
    if (t < GPB) {
        int gi = t, n = n0 + gi;
        int x = x0 + gi;
        float cy = -1.f + (2.f*y + 1.f) / (float)HI;
        float cx = -1.f + (2.f*x + 1.f) / (float)WI;
        float xyy = cy + tanhf(outv[gi][0]) * OFF_SCALE;
        float xyx = cx + tanhf(outv[gi][1]) * OFF_SCALE;
        float pxp = (xyx + 1.f) * 0.5f * (float)WT - 0.5f;
        float pyp = (xyy + 1.f) * 0.5f * (float)HT - 0.5f;
        float t2 = outv[gi][2], t3 = outv[gi][3];
        float s0 = (t2 > 0.f ? t2 : expf(t2) - 1.f) + 1.5f;
        float s1 = (t3 > 0.f ? t3 : expf(t3) - 1.f) + 1.5f;
        float rot = tanhf(outv[gi][4]) * 3.14159265358979323846f;
        float cr = cosf(rot), sr = sinf(rot);
        float sx2 = s0*s0, sy2 = s1*s1;
        float cov_a = cr*cr*sx2 + sr*sr*sy2;
        float cov_b = cr*sr*(sx2 - sy2);
        float cov_c = sr*sr*sx2 + cr*cr*sy2;
        float det = cov_a*cov_c - cov_b*cov_b;
        float conA = cov_c / det, conB = -cov_b / det, conC = cov_a / det;
        float c0 = 1.f/(1.f + expf(-outv[gi][5]));
        float c1 = 1.f/(1.f + expf(-outv[gi][6]));
        float c2 = 1.f/(1.f + expf(-outv[gi][7]));
        float rx = sqrtf(2.f * LN255 * cov_a);
        float ry = sqrtf(2.f * LN255 * cov_c);
        ga[n] = make_float4(pxp, pyp, conA, conB);
        gb[n] = make_float4(conC, c0, c1, c2);
        gt[n] = make_float4(pxp, pyp, rx, ry);
    }
}

// ---- render: 8x8 tiles, 256 threads = 64 pixels x 4 survivor slices ----
__global__ __launch_bounds__(256) void render_kernel(
    const float4* __restrict__ ga, const float4* __restrict__ gb,
    const float4* __restrict__ gt, float* __restrict__ out)
{
    __shared__ unsigned short sidx[NG];
    __shared__ int ns;
    __shared__ __align__(16) float4 lp0[256];
    __shared__ __align__(16) float4 lp1[256];
    __shared__ __align__(16) float4 sred[3][64];    // slices 1..3 partials

    const int t    = threadIdx.x;
    const int q    = t >> 6;                  // survivor slice 0..3 (wave-uniform)
    const int p    = t & 63;                  // pixel within 8x8 tile
    const int b    = blockIdx.y;
    const int tile = blockIdx.x;              // 0..143
    const int tx   = (tile % (WT/RTS)) * RTS;
    const int ty   = (tile / (WT/RTS)) * RTS;
    const float cx = tx + (RTS-1)*0.5f;
    const float cy = ty + (RTS-1)*0.5f;
    const float hw = (RTS-1)*0.5f;
    const int lane = t & 63;
    const unsigned long long lmask = (1ull << lane) - 1ull;

    if (t == 0) ns = 0;
    __syncthreads();

    // ---- phase 1: bbox cull, per-wave ballot compaction (uniform 9 trips) ----
    for (int base = 0; base < NG; base += 256) {
        int n = base + t;
        float4 v = gt[b*NG + n];              // px, py, rx, ry
        bool keep = (fabsf(v.x - cx) <= v.z + hw) && (fabsf(v.y - cy) <= v.w + hw);
        unsigned long long mask = __ballot(keep);
        int cnt = __popcll(mask);
        int wbase = 0;
        if (lane == 0 && cnt > 0) wbase = atomicAdd(&ns, cnt);
        wbase = __shfl(wbase, 0);
        if (keep) sidx[wbase + __popcll(mask & lmask)] = (unsigned short)n;
    }
    __syncthreads();
    const int total = ns;

    const float gxf = (float)(tx + (p & (RTS-1)));
    const float gyf = (float)(ty + (p >> 3));
    float ra = 0.f, gg = 0.f, ba = 0.f, aa = 0.f;

    // ---- phase 2: chunks of 256 staged to LDS; slice q walks j = q (mod 4) ----
    for (int base = 0; base < total; base += 256) {
        int cn = min(256, total - base);
        __syncthreads();
        if (t < cn) {
            int n = b*NG + sidx[base + t];
            lp0[t] = ga[n];                   // px, py, conA, conB
            lp1[t] = gb[n];                   // conC, r, g, b
        }
        __syncthreads();
        for (int j = q; j < cn; j += 4) {
            float4 c0 = lp0[j];
            float4 c1 = lp1[j];
            float dx = gxf - c0.x, dy = gyf - c0.y;
            float sg = 0.5f*(c0.z*dx*dx + c1.x*dy*dy) + c0.w*(dx*dy);
            float w = __expf(-sg);
            float alpha = (sg >= 0.f && w >= A_MIN) ? fminf(w, A_MAX) : 0.f;
            ra += alpha * c1.y;
            gg += alpha * c1.z;
            ba += alpha * c1.w;
            aa += alpha;
        }
    }

    // ---- combine the 4 slices ----
    if (q > 0) sred[q-1][p] = make_float4(ra, gg, ba, aa);
    __syncthreads();
    if (q == 0) {
        #pragma unroll
        for (int s = 0; s < 3; ++s) {
            float4 v = sred[s][p];
            ra += v.x; gg += v.y; ba += v.z; aa += v.w;
        }
        float T = fminf(fmaxf(1.f - aa, 0.f), 1.f);
        int o = (b*PT + (ty + (p >> 3))*WT + tx + (p & (RTS-1))) * 3;
        out[o + 0] = ra + T;
        out[o + 1] = gg + T;
        out[o + 2] = ba + T;
    }
}

extern "C" void kernel_launch(void* const* d_in, const int* in_sizes, int n_in,
                              void* d_out, int out_size, void* d_ws, size_t ws_size,
                              hipStream_t stream)
{
    const float* inp   = (const float*)d_in[0];
    const float* enc_w = (const float*)d_in[1];
    const float* enc_b = (const float*)d_in[2];
    const float* ow1 = (const float*)d_in[3];
    const float* ob1 = (const float*)d_in[4];
    const float* ow2 = (const float*)d_in[5];
    const float* ob2 = (const float*)d_in[6];
    const float* sw1 = (const float*)d_in[7];
    const float* sb1 = (const float*)d_in[8];
    const float* sw2 = (const float*)d_in[9];
    const float* sb2 = (const float*)d_in[10];
    const float* rw1 = (const float*)d_in[11];
    const float* rb1 = (const float*)d_in[12];
    const float* rw2 = (const float*)d_in[13];
    const float* rb2 = (const float*)d_in[14];
    const float* cw1 = (const float*)d_in[15];
    const float* cb1 = (const float*)d_in[16];
    const float* cw2 = (const float*)d_in[17];
    const float* cb2 = (const float*)d_in[18];

    float4* ga = (float4*)d_ws;            // NT float4
    float4* gb = ga + NT;                  // NT float4
    float4* gt = gb + NT;                  // NT float4

    param_kernel<<<NT/GPB, 256, 0, stream>>>(inp, enc_w, enc_b,
                                             ow1, ob1, ow2, ob2,
                                             sw1, sb1, sw2, sb2,
                                             rw1, rb1, rw2, rb2,
                                             cw1, cb1, cw2, cb2,
                                             ga, gb, gt);
    render_kernel<<<dim3((WT/RTS)*(HT/RTS), B_SZ), 256, 0, stream>>>(ga, gb, gt, (float*)d_out);
}

// Round 19
// 28.326 us; speedup vs baseline: 1.0268x; 1.0268x over previous
//
#include <hip/hip_runtime.h>
#include <math.h>

// ---- compile-time problem constants (from setup_inputs) ----
#define B_SZ 2
#define HI 48
#define WI 48
#define NG (HI*WI)          // 2304 gaussians per image
#define NT (B_SZ*NG)        // 4608 total gaussians
#define HIDN 256
#define HT 96
#define WT 96
#define PT (HT*WT)          // 9216 pixels per image
#define FACTOR 2.0f         // max(96/48, 96/48)
#define OFF_SCALE 0.125f    // 3 * (2*factor / max(Ht,Wt))
#define A_MIN (1.0f/255.0f)
#define A_MAX 0.99f
#define LN255 5.54126354516f   // ln(255): w >= 1/255 <=> sigma <= LN255

#define GPB 6               // gaussians per block: 4608/6 = 768 blocks = 3/CU EXACTLY
                            // (6 | 48 -> same row; 6 | 2304 -> no image straddle)
#define RTS 8               // render tile size (8x8 px, 64 px x 4 slices, 256 thr)

// ws layout: ga[NT] f4 | gb[NT] f4 | gt[NT] f4

__global__ __launch_bounds__(256, 3) void param_kernel(
    const float* __restrict__ inp, const float* __restrict__ enc_w, const float* __restrict__ enc_b,
    const float* __restrict__ ow1, const float* __restrict__ ob1, const float* __restrict__ ow2, const float* __restrict__ ob2,
    const float* __restrict__ sw1, const float* __restrict__ sb1, const float* __restrict__ sw2, const float* __restrict__ sb2,
    const float* __restrict__ rw1, const float* __restrict__ rb1, const float* __restrict__ rw2, const float* __restrict__ rb2,
    const float* __restrict__ cw1, const float* __restrict__ cb1, const float* __restrict__ cw2, const float* __restrict__ cb2,
    float4* __restrict__ ga, float4* __restrict__ gb, float4* __restrict__ gt)
{
    __shared__ float sinp[3][3][12];                 // input patch: 3ch x 3 rows x 8 cols (pad 12)
    __shared__ __align__(16) float feat[GPB][68];    // conv output, float4-readable
    __shared__ __align__(16) float hid[4][GPB][260]; // layer-1 output, stride 260
    __shared__ __align__(16) float w2t[8][260];      // transposed layer-2 weights: w2t[o][k]
    __shared__ float red[192];
    __shared__ float outv[GPB][8];

    const int t  = threadIdx.x;
    const int n0 = blockIdx.x * GPB;
    const int b  = n0 / NG;
    const int pix0 = n0 % NG;
    const int y  = pix0 / WI;
    const int x0 = pix0 % WI;     // block's 6 pixels: (y, x0..x0+5), same row

    // ---- stage input patch + transposed w2 to LDS ----
    if (t < 72) {                 // 3 ch x 3 rows x 8 cols
        int c = t / 24, r = (t / 8) % 3, cc = t % 8;
        int yy = y + r - 1;
        int xx = x0 + cc - 1;
        float v = 0.f;
        if (yy >= 0 && yy < HI && xx >= 0 && xx < WI)
            v = inp[((b*3 + c)*HI + yy)*WI + xx];
        sinp[c][r][cc] = v;
    }
    for (int i = t; i < 2048; i += 256) {
        int o = i >> 8, k = i & 255;
        float v;
        if (o < 2)      v = ow2[k*2 + o];
        else if (o < 4) v = sw2[k*2 + (o-2)];
        else if (o < 5) v = rw2[k];
        else            v = cw2[k*3 + (o-5)];
        w2t[o][k] = v;
    }
    __syncthreads();

    // ---- conv 3x3 SAME: weights in VGPRs (o = t&63 invariant); 384 tasks ----
    {
        const int o = t & 63;
        float w[27];
        #pragma unroll
        for (int j = 0; j < 27; ++j) w[j] = enc_w[o*27 + j];
        const float bias = enc_b[o];
        #pragma unroll
        for (int rep = 0; rep < 2; ++rep) {
            int idx = rep * 256 + t;
            if (idx < GPB*64) {
                int gi = idx >> 6;
                float acc = bias;
                #pragma unroll
                for (int c = 0; c < 3; ++c)
                    #pragma unroll
                    for (int ky = 0; ky < 3; ++ky)
                        #pragma unroll
                        for (int kx = 0; kx < 3; ++kx)
                            acc += w[c*9 + ky*3 + kx] * sinp[c][ky][gi + kx];
                feat[gi][o] = acc;
            }
        }
    }
    __syncthreads();

    // ---- layer 1: thread = (mlp m, h-quad); software-pipelined weight loads ----
    const int m  = t >> 6;          // wave-uniform
    const int h0 = (t & 63) * 4;
    {
        const float* __restrict__ w1 = (m == 0) ? ow1 : (m == 1) ? sw1 : (m == 2) ? rw1 : cw1;
        const float* __restrict__ b1 = (m == 0) ? ob1 : (m == 1) ? sb1 : (m == 2) ? rb1 : cb1;
        float acc[4][GPB];
        #pragma unroll
        for (int hh = 0; hh < 4; ++hh)
            #pragma unroll
            for (int gi = 0; gi < GPB; ++gi) acc[hh][gi] = 0.f;

        // prefetch group 0
        float4 wA0 = *(const float4*)&w1[0*HIDN + h0];
        float4 wA1 = *(const float4*)&w1[1*HIDN + h0];
        float4 wA2 = *(const float4*)&w1[2*HIDN + h0];
        float4 wA3 = *(const float4*)&w1[3*HIDN + h0];

        for (int it = 0; it < 15; ++it) {           // groups 0..14, prefetch it+1
            float4 wB0 = *(const float4*)&w1[(it*4 + 4)*HIDN + h0];
            float4 wB1 = *(const float4*)&w1[(it*4 + 5)*HIDN + h0];
            float4 wB2 = *(const float4*)&w1[(it*4 + 6)*HIDN + h0];
            float4 wB3 = *(const float4*)&w1[(it*4 + 7)*HIDN + h0];
            #pragma unroll
            for (int gi = 0; gi < GPB; ++gi) {
                float4 f = *(const float4*)&feat[gi][it*4];
                acc[0][gi] += f.x*wA0.x + f.y*wA1.x + f.z*wA2.x + f.w*wA3.x;
                acc[1][gi] += f.x*wA0.y + f.y*wA1.y + f.z*wA2.y + f.w*wA3.y;
                acc[2][gi] += f.x*wA0.z + f.y*wA1.z + f.z*wA2.z + f.w*wA3.z;
                acc[3][gi] += f.x*wA0.w + f.y*wA1.w + f.z*wA2.w + f.w*wA3.w;
            }
            wA0 = wB0; wA1 = wB1; wA2 = wB2; wA3 = wB3;
        }
        // peeled group 15 (k = 60..63)
        #pragma unroll
        for (int gi = 0; gi < GPB; ++gi) {
            float4 f = *(const float4*)&feat[gi][60];
            acc[0][gi] += f.x*wA0.x + f.y*wA1.x + f.z*wA2.x + f.w*wA3.x;
            acc[1][gi] += f.x*wA0.y + f.y*wA1.y + f.z*wA2.y + f.w*wA3.y;
            acc[2][gi] += f.x*wA0.z + f.y*wA1.z + f.z*wA2.z + f.w*wA3.z;
            acc[3][gi] += f.x*wA0.w + f.y*wA1.w + f.z*wA2.w + f.w*wA3.w;
        }

        // effective bias: b1 + FACTOR * w1[k=64 row]  (feat[64] == FACTOR const)
        float4 bb = *(const float4*)&b1[h0];
        float4 wl = *(const float4*)&w1[64*HIDN + h0];
        bb.x += FACTOR * wl.x; bb.y += FACTOR * wl.y;
        bb.z += FACTOR * wl.z; bb.w += FACTOR * wl.w;
        #pragma unroll
        for (int gi = 0; gi < GPB; ++gi) {
            float4 hv;
            hv.x = fmaxf(acc[0][gi] + bb.x, 0.f);
            hv.y = fmaxf(acc[1][gi] + bb.y, 0.f);
            hv.z = fmaxf(acc[2][gi] + bb.z, 0.f);
            hv.w = fmaxf(acc[3][gi] + bb.w, 0.f);
            *(float4*)&hid[m][gi][h0] = hv;
        }
    }
    __syncthreads();

    // ---- layer 2: 48 (gi,o) pairs x 4 k-chunks = 192 tasks ----
    if (t < 192) {
        int pair = t % 48, q = t / 48;
        int o = pair & 7, gi = pair >> 3;
        int mm = (o < 2) ? 0 : (o < 4) ? 1 : (o < 5) ? 2 : 3;
        float p = 0.f;
        int k0 = q * 64;
        #pragma unroll
        for (int kk = 0; kk < 16; ++kk) {
            float4 hv = *(const float4*)&hid[mm][gi][k0 + kk*4];
            float4 wv = *(const float4*)&w2t[o][k0 + kk*4];
            p += hv.x*wv.x + hv.y*wv.y + hv.z*wv.z + hv.w*wv.w;
        }
        red[t] = p;
    }
    __syncthreads();
    if (t < 48) {
        int o = t & 7;
        float v = red[t] + red[t+48] + red[t+96] + red[t+144];
        float b2 = (o < 2) ? ob2[o] : (o < 4) ? sb2[o-2] : (o < 5) ? rb2[0] : cb2[o-5];
        outv[t >> 3][o] = v + b2;
    }
    __syncthreads();

    // ---- activations + projection + conic + cull radii ----
    if (t < GPB) {
        int gi = t, n = n0 + gi;
        int x = x0 + gi;
        float cy = -1.f + (2.f*y + 1.f) / (float)HI;
        float cx = -1.f + (2.f*x + 1.f) / (float)WI;
        float xyy = cy + tanhf(outv[gi][0]) * OFF_SCALE;
        float xyx = cx + tanhf(outv[gi][1]) * OFF_SCALE;
        float pxp = (xyx + 1.f) * 0.5f * (float)WT - 0.5f;
        float pyp = (xyy + 1.f) * 0.5f * (float)HT - 0.5f;
        float t2 = outv[gi][2], t3 = outv[gi][3];
        float s0 = (t2 > 0.f ? t2 : expf(t2) - 1.f) + 1.5f;
        float s1 = (t3 > 0.f ? t3 : expf(t3) - 1.f) + 1.5f;
        float rot = tanhf(outv[gi][4]) * 3.14159265358979323846f;
        float cr = cosf(rot), sr = sinf(rot);
        float sx2 = s0*s0, sy2 = s1*s1;
        float cov_a = cr*cr*sx2 + sr*sr*sy2;
        float cov_b = cr*sr*(sx2 - sy2);
        float cov_c = sr*sr*sx2 + cr*cr*sy2;
        float det = cov_a*cov_c - cov_b*cov_b;
        float conA = cov_c / det, conB = -cov_b / det, conC = cov_a / det;
        float c0 = 1.f/(1.f + expf(-outv[gi][5]));
        float c1 = 1.f/(1.f + expf(-outv[gi][6]));
        float c2 = 1.f/(1.f + expf(-outv[gi][7]));
        float rx = sqrtf(2.f * LN255 * cov_a);
        float ry = sqrtf(2.f * LN255 * cov_c);
        ga[n] = make_float4(pxp, pyp, conA, conB);
        gb[n] = make_float4(conC, c0, c1, c2);
        gt[n] = make_float4(pxp, pyp, rx, ry);
    }
}

// ---- render: 8x8 tiles, 256 threads = 64 pixels x 4 survivor slices ----
__global__ __launch_bounds__(256) void render_kernel(
    const float4* __restrict__ ga, const float4* __restrict__ gb,
    const float4* __restrict__ gt, float* __restrict__ out)
{
    __shared__ unsigned short sidx[NG];
    __shared__ int ns;
    __shared__ __align__(16) float4 lp0[256];
    __shared__ __align__(16) float4 lp1[256];
    __shared__ __align__(16) float4 sred[3][64];    // slices 1..3 partials

    const int t    = threadIdx.x;
    const int q    = t >> 6;                  // survivor slice 0..3 (wave-uniform)
    const int p    = t & 63;                  // pixel within 8x8 tile
    const int b    = blockIdx.y;
    const int tile = blockIdx.x;              // 0..143
    const int tx   = (tile % (WT/RTS)) * RTS;
    const int ty   = (tile / (WT/RTS)) * RTS;
    const float cx = tx + (RTS-1)*0.5f;
    const float cy = ty + (RTS-1)*0.5f;
    const float hw = (RTS-1)*0.5f;
    const int lane = t & 63;
    const unsigned long long lmask = (1ull << lane) - 1ull;

    if (t == 0) ns = 0;
    __syncthreads();

    // ---- phase 1: bbox cull, per-wave ballot compaction (uniform 9 trips) ----
    for (int base = 0; base < NG; base += 256) {
        int n = base + t;
        float4 v = gt[b*NG + n];              // px, py, rx, ry
        bool keep = (fabsf(v.x - cx) <= v.z + hw) && (fabsf(v.y - cy) <= v.w + hw);
        unsigned long long mask = __ballot(keep);
        int cnt = __popcll(mask);
        int wbase = 0;
        if (lane == 0 && cnt > 0) wbase = atomicAdd(&ns, cnt);
        wbase = __shfl(wbase, 0);
        if (keep) sidx[wbase + __popcll(mask & lmask)] = (unsigned short)n;
    }
    __syncthreads();
    const int total = ns;

    const float gxf = (float)(tx + (p & (RTS-1)));
    const float gyf = (float)(ty + (p >> 3));
    float ra = 0.f, gg = 0.f, ba = 0.f, aa = 0.f;

    // ---- phase 2: chunks of 256 staged to LDS; slice q walks j = q (mod 4) ----
    for (int base = 0; base < total; base += 256) {
        int cn = min(256, total - base);
        __syncthreads();
        if (t < cn) {
            int n = b*NG + sidx[base + t];
            lp0[t] = ga[n];                   // px, py, conA, conB
            lp1[t] = gb[n];                   // conC, r, g, b
        }
        __syncthreads();
        for (int j = q; j < cn; j += 4) {
            float4 c0 = lp0[j];
            float4 c1 = lp1[j];
            float dx = gxf - c0.x, dy = gyf - c0.y;
            float sg = 0.5f*(c0.z*dx*dx + c1.x*dy*dy) + c0.w*(dx*dy);
            float w = __expf(-sg);
            float alpha = (sg >= 0.f && w >= A_MIN) ? fminf(w, A_MAX) : 0.f;
            ra += alpha * c1.y;
            gg += alpha * c1.z;
            ba += alpha * c1.w;
            aa += alpha;
        }
    }

    // ---- combine the 4 slices ----
    if (q > 0) sred[q-1][p] = make_float4(ra, gg, ba, aa);
    __syncthreads();
    if (q == 0) {
        #pragma unroll
        for (int s = 0; s < 3; ++s) {
            float4 v = sred[s][p];
            ra += v.x; gg += v.y; ba += v.z; aa += v.w;
        }
        float T = fminf(fmaxf(1.f - aa, 0.f), 1.f);
        int o = (b*PT + (ty + (p >> 3))*WT + tx + (p & (RTS-1))) * 3;
        out[o + 0] = ra + T;
        out[o + 1] = gg + T;
        out[o + 2] = ba + T;
    }
}

extern "C" void kernel_launch(void* const* d_in, const int* in_sizes, int n_in,
                              void* d_out, int out_size, void* d_ws, size_t ws_size,
                              hipStream_t stream)
{
    const float* inp   = (const float*)d_in[0];
    const float* enc_w = (const float*)d_in[1];
    const float* enc_b = (const float*)d_in[2];
    const float* ow1 = (const float*)d_in[3];
    const float* ob1 = (const float*)d_in[4];
    const float* ow2 = (const float*)d_in[5];
    const float* ob2 = (const float*)d_in[6];
    const float* sw1 = (const float*)d_in[7];
    const float* sb1 = (const float*)d_in[8];
    const float* sw2 = (const float*)d_in[9];
    const float* sb2 = (const float*)d_in[10];
    const float* rw1 = (const float*)d_in[11];
    const float* rb1 = (const float*)d_in[12];
    const float* rw2 = (const float*)d_in[13];
    const float* rb2 = (const float*)d_in[14];
    const float* cw1 = (const float*)d_in[15];
    const float* cb1 = (const float*)d_in[16];
    const float* cw2 = (const float*)d_in[17];
    const float* cb2 = (const float*)d_in[18];

    float4* ga = (float4*)d_ws;            // NT float4
    float4* gb = ga + NT;                  // NT float4
    float4* gt = gb + NT;                  // NT float4

    param_kernel<<<NT/GPB, 256, 0, stream>>>(inp, enc_w, enc_b,
                                             ow1, ob1, ow2, ob2,
                                             sw1, sb1, sw2, sb2,
                                             rw1, rb1, rw2, rb2,
                                             cw1, cb1, cw2, cb2,
                                             ga, gb, gt);
    render_kernel<<<dim3((WT/RTS)*(HT/RTS), B_SZ), 256, 0, stream>>>(ga, gb, gt, (float*)d_out);
}